// Round 11
// baseline (521.482 us; speedup 1.0000x reference)
//
#include <hip/hip_runtime.h>

#define NEGV -1e9f

// workspace layout (float offsets)
#define OFF_X1   0u               // 1048576  emb@W_ih^T + b
#define OFF_XX   1048576u         // 1048576  emb@Wx^T + b_cell
#define OFF_A    2097152u         // 262144   Aemb = Ws_b + emb@Ws3^T (row-major)
#define OFF_SH   2359296u         // 262144   shared LSTM outputs (atomic stores)
#define OFF_HX2  3670016u         // 16384 floats = 8192 u64 (k2 h exchange)
#define OFF_HX4  3686400u         // 16384 floats (k4 h exchange)
#define OFF_PSI  3702784u         // 32768 floats = 2 slots x 16 x 512 u64 (psi exchange)
#define OFF_FLG  3735552u         // 256 u32 sh-done flags

__device__ __forceinline__ float sigf(float x) { return 1.f / (1.f + __expf(-x)); }
__device__ __forceinline__ float tanhfast(float x) {
  float e = __expf(2.f * x);
  return 1.f - __fdividef(2.f, e + 1.f);
}

__device__ __forceinline__ unsigned long long gloadU64(const unsigned long long* p) {
  return __hip_atomic_load(p, __ATOMIC_RELAXED, __HIP_MEMORY_SCOPE_AGENT);
}
__device__ __forceinline__ void gstoreU64(unsigned long long* p, unsigned long long v) {
  __hip_atomic_store(p, v, __ATOMIC_RELAXED, __HIP_MEMORY_SCOPE_AGENT);
}
__device__ __forceinline__ float gloadF(const float* p) {
  return __hip_atomic_load(p, __ATOMIC_RELAXED, __HIP_MEMORY_SCOPE_AGENT);
}
__device__ __forceinline__ void gstoreF(float* p, float v) {
  __hip_atomic_store(p, v, __ATOMIC_RELAXED, __HIP_MEMORY_SCOPE_AGENT);
}
__device__ __forceinline__ unsigned gloadAcq(const unsigned* p) {
  return __hip_atomic_load(p, __ATOMIC_ACQUIRE, __HIP_MEMORY_SCOPE_AGENT);
}
__device__ __forceinline__ void gstoreRel(unsigned* p, unsigned v) {
  __hip_atomic_store(p, v, __ATOMIC_RELEASE, __HIP_MEMORY_SCOPE_AGENT);
}
__device__ __forceinline__ unsigned long long packTV(unsigned tag, float v) {
  return ((unsigned long long)tag << 32) | (unsigned long long)__float_as_uint(v);
}

// 16-row x 128-col output tile GEMM helper, K=256. eL: [16][260], wL: [128][68]
__device__ __forceinline__ void tile_mm(const float* __restrict__ W, int ldw, int wcol0,
                                        int j0, const float* eL, float* wL, float acc[8]) {
  const int i = threadIdx.x >> 4, jj = threadIdx.x & 15;
  for (int kc = 0; kc < 4; ++kc) {
    __syncthreads();
    const int k0 = kc * 64;
    #pragma unroll
    for (int m = 0; m < 32; ++m) {
      int v = threadIdx.x + (m << 8);
      int row = v >> 6, col = v & 63;
      wL[row * 68 + col] = W[(j0 + row) * ldw + wcol0 + k0 + col];
    }
    __syncthreads();
    const float* ebase = eL + i * 260 + k0;
    #pragma unroll 4
    for (int k4 = 0; k4 < 16; ++k4) {
      float4 e4 = *(const float4*)(ebase + k4 * 4);
      #pragma unroll
      for (int u = 0; u < 8; ++u) {
        float4 w4 = *(const float4*)(wL + (jj + (u << 4)) * 68 + k4 * 4);
        acc[u] += e4.x * w4.x + e4.y * w4.y + e4.z * w4.z + e4.w * w4.w;
      }
    }
  }
}

// K1: emb gather + X1 = emb@W_ih^T + (b_ih+b_hh); Xx = emb@Wx^T + b_cell;
//     Aemb = emb@Ws3^T + Ws_b. Zero-inits all exchange buffers + flags.
__global__ __launch_bounds__(256) void k1_precompute(
    const int* __restrict__ x, const float* __restrict__ embed,
    const float* __restrict__ W_ih, const float* __restrict__ b_ih,
    const float* __restrict__ b_hh, const float* __restrict__ Ws_w,
    const float* __restrict__ Ws_b, const float* __restrict__ Wx,
    const float* __restrict__ b_cell, float* __restrict__ ws) {
  __shared__ float eL[16 * 260];
  __shared__ float wL[128 * 68];
  const int rt = blockIdx.x / 18, jb = blockIdx.x % 18;
  if (blockIdx.x == 0) {
    for (int i = threadIdx.x; i < 65792; i += 256) ws[OFF_HX2 + i] = 0.f;
  }
  for (int i = 0; i < 16; ++i) {
    int xi = x[rt * 16 + i];
    eL[i * 260 + threadIdx.x] = embed[xi * 256 + threadIdx.x];
  }
  const float* W; const float* bias1; const float* bias2 = nullptr;
  int ldw, wcol0, j0, ostride; float* out;
  if (jb < 8)       { W = W_ih; ldw = 256; wcol0 = 0;   j0 = jb * 128;        out = ws + OFF_X1; ostride = 1024; bias1 = b_ih; bias2 = b_hh; }
  else if (jb < 16) { W = Wx;   ldw = 256; wcol0 = 0;   j0 = (jb - 8) * 128;  out = ws + OFF_XX; ostride = 1024; bias1 = b_cell; }
  else              { W = Ws_w; ldw = 768; wcol0 = 512; j0 = (jb - 16) * 128; out = ws + OFF_A;  ostride = 256;  bias1 = Ws_b; }
  float acc[8];
  #pragma unroll
  for (int u = 0; u < 8; ++u) acc[u] = 0.f;
  tile_mm(W, ldw, wcol0, j0, eL, wL, acc);
  const int i = threadIdx.x >> 4, jj = threadIdx.x & 15;
  const int r = rt * 16 + i;
  #pragma unroll
  for (int u = 0; u < 8; ++u) {
    int j = j0 + jj + (u << 4);
    float bv = bias1[j] + (bias2 ? bias2[j] : 0.f);
    out[r * ostride + j] = acc[u] + bv;
  }
}

// K_FUSED: per batch-group (8 WGs x 512 thr): shared LSTM -> local k3 -> task LSTM.
__global__ __launch_bounds__(512) void k_fused(
    const int* __restrict__ mask, const float* __restrict__ W_hh,
    const float* __restrict__ Ws_w, const float* __restrict__ Us_w,
    const float* __restrict__ Wh, const float* __restrict__ Wm,
    const float* __restrict__ fc_w, const float* __restrict__ fc_b,
    float* __restrict__ ws, float* __restrict__ out) {
  const int b = blockIdx.x & 15, j = blockIdx.x >> 4;
  const int t = threadIdx.x;
  const int w = t >> 6, l = t & 63;

  __shared__ __align__(16) float bigL[256 * 65];   // 66560B: x1L (phase A) / shT (phase B)
  __shared__ __align__(16) float aTo[32 * 65];     // 8320B  own A^T chunk [kk][s]
  __shared__ __align__(16) float swmB[10240];      // 40960B [s/16][r][16]
  __shared__ __align__(16) float hL[256];
  __shared__ float hwOwn[32];
  __shared__ float usOwn[32];
  __shared__ float part[512];
  __shared__ float psiA[512];
  __shared__ __align__(16) float attL[64];
  __shared__ float gA[128];
  __shared__ float redL[4];
  __shared__ int   mL[64];

  float* shg = ws + OFF_SH;
  const float* X1   = ws + OFF_X1;
  const float* Xx   = ws + OFF_XX;
  const float* Aemb = ws + OFF_A;
  unsigned long long* hx2  = (unsigned long long*)(ws + OFF_HX2);
  unsigned long long* hx4  = (unsigned long long*)(ws + OFF_HX4);
  unsigned long long* psiX = (unsigned long long*)(ws + OFF_PSI);
  unsigned* flg = (unsigned*)(ws + OFF_FLG);

  // ================= Phase A: shared LSTM (R5 k2 verbatim) =================
  {
    const int rl = t >> 2, q = t & 3;
    const int grow = ((rl >> 5) << 8) + (j << 5) + (rl & 31);
    float4 wv[16];
    {
      const float* wp = W_hh + grow * 256 + (q << 6);
      #pragma unroll
      for (int m = 0; m < 16; ++m) wv[m] = *(const float4*)(wp + 4 * m);
    }
    for (int v = t; v < 8192; v += 512) {
      int st = v >> 7, rr = v & 127;
      int col = ((rr >> 5) << 8) + (j << 5) + (rr & 31);
      bigL[v] = X1[(b * 64 + st) * 1024 + col];
    }
    float c_reg = 0.f;
    __syncthreads();
    for (int st = 0; st < 64; ++st) {
      if (t < 256) {
        const unsigned long long* p = hx2 + (unsigned)(st & 1) * 4096u + b * 256 + t;
        unsigned long long v = gloadU64(p);
        while ((unsigned)(v >> 32) < (unsigned)st) v = gloadU64(p);
        hL[t] = __uint_as_float((unsigned)v);
      }
      __syncthreads();
      const float* hp = hL + (q << 6);
      float p = 0.f;
      #pragma unroll
      for (int m = 0; m < 16; ++m) {
        float4 h4 = *(const float4*)(hp + 4 * m);
        p += wv[m].x * h4.x + wv[m].y * h4.y + wv[m].z * h4.z + wv[m].w * h4.w;
      }
      p += __shfl_xor(p, 1); p += __shfl_xor(p, 2);
      if (q == 0) gA[rl] = p + bigL[(st << 7) + rl];
      __syncthreads();
      if (t < 32) {
        float gi = gA[t], gf = gA[32 + t], gg = gA[64 + t], go = gA[96 + t];
        c_reg = sigf(gf) * c_reg + sigf(gi) * tanhfast(gg);
        float hn = sigf(go) * tanhfast(c_reg);
        gstoreF(shg + (b * 64 + st) * 256 + (j << 5) + t, hn);
        gstoreU64(hx2 + (unsigned)((st + 1) & 1) * 4096u + b * 256 + (j << 5) + t,
                  packTV(st + 1, hn));
      }
    }
    __syncthreads();                     // drains all waves' sh stores (vmcnt)
    if (t == 0) gstoreRel(flg + b * 16 + j, 1u);
  }
  // ---- transition: wait for the whole group's sh ----
  if (t < 8) { while (gloadAcq(flg + b * 16 + t) < 1u) {} }
  __syncthreads();

  // ================= Phase B: local k3 (shT -> aTo, swmB) =================
  for (int v = t; v < 16384; v += 512) {
    int s = v >> 8, m = v & 255;
    bigL[m * 65 + s] = gloadF(shg + (unsigned)(b * 64 + s) * 256u + m);
  }
  __syncthreads();
  // aTo: wave w owns kk in [4w, 4w+4); lane l = s
  #pragma unroll
  for (int i2 = 0; i2 < 4; ++i2) {
    int kk = (w << 2) + i2;
    int gk = (j << 5) + kk;
    const float* wr = Ws_w + gk * 768;     // Ws1 row gk
    float acc = 0.f;
    #pragma unroll 4
    for (int m = 0; m < 256; m += 4) {
      float4 w4 = *(const float4*)(wr + m);
      acc += w4.x * bigL[m * 65 + l]       + w4.y * bigL[(m + 1) * 65 + l]
           + w4.z * bigL[(m + 2) * 65 + l] + w4.w * bigL[(m + 3) * 65 + l];
    }
    aTo[kk * 65 + l] = acc + Aemb[(b * 64 + l) * 256 + gk];
  }
  // swmB: wave w owns local cols c = 8*i2 + w; lane l = s
  for (int i2 = 0; i2 < 16; ++i2) {
    int c = (i2 << 3) + w;
    int gcol = ((c >> 5) << 8) + (j << 5) + (c & 31);
    const float* wr = Wm + gcol * 256;
    float acc = 0.f;
    #pragma unroll 4
    for (int m = 0; m < 256; m += 4) {
      float4 w4 = *(const float4*)(wr + m);
      acc += w4.x * bigL[m * 65 + l]       + w4.y * bigL[(m + 1) * 65 + l]
           + w4.z * bigL[(m + 2) * 65 + l] + w4.w * bigL[(m + 3) * 65 + l];
    }
    swmB[(l >> 4) * 2560 + c * 20 + (l & 15)] = acc;
  }
  __syncthreads();

  // ================= Phase C: task LSTM (R5 k4 verbatim) =================
  {
    const int rl = t >> 2, q = t & 3;
    const int grow = ((rl >> 5) << 8) + (j << 5) + (rl & 31);
    const int hwrow = t >> 4, hwc = t & 15;
    const int kq = t >> 6, sl = t & 63;

    float4 w2v[4];    // Ws2 row (32j+hwrow), cols hwc*16..+16
    {
      const float* p2 = Ws_w + (j * 32 + hwrow) * 768 + 256 + (hwc << 4);
      #pragma unroll
      for (int m = 0; m < 4; ++m) w2v[m] = *(const float4*)(p2 + 4 * m);
    }
    float4 whv[16];   // Wh quarter-row (grow, cols q*64..+64)
    {
      const float* pw = Wh + grow * 256 + (q << 6);
      #pragma unroll
      for (int m = 0; m < 16; ++m) whv[m] = *(const float4*)(pw + 4 * m);
    }
    if (t < 32) usOwn[t] = Us_w[j * 32 + t];
    if (t < 64) mL[t] = mask[b * 64 + t];
    float c_reg = 0.f;
    __syncthreads();

    for (int st = 0; st < 64; ++st) {
      float xx_r = 0.f;
      if (q == 0) xx_r = Xx[(b * 64 + st) * 1024 + grow];
      if (t < 256) {
        const unsigned long long* p = hx4 + (unsigned)(st & 1) * 4096u + b * 256 + t;
        unsigned long long v = gloadU64(p);
        while ((unsigned)(v >> 32) < (unsigned)st) v = gloadU64(p);
        hL[t] = __uint_as_float((unsigned)v);
      }
      __syncthreads();
      // hw own rows: 16 threads/row
      {
        const float* hp = hL + (hwc << 4);
        float p = 0.f;
        #pragma unroll
        for (int m = 0; m < 4; ++m) {
          float4 h4 = *(const float4*)(hp + 4 * m);
          p += w2v[m].x * h4.x + w2v[m].y * h4.y + w2v[m].z * h4.z + w2v[m].w * h4.w;
        }
        p += __shfl_xor(p, 1); p += __shfl_xor(p, 2);
        p += __shfl_xor(p, 4); p += __shfl_xor(p, 8);
        if (hwc == 0) hwOwn[hwrow] = p;
      }
      __syncthreads();
      // psi partials: lane owns s, wave owns 4 k's
      {
        float ps = 0.f;
        #pragma unroll
        for (int i2 = 0; i2 < 4; ++i2) {
          int kk = (kq << 2) + i2;
          ps += usOwn[kk] * tanhfast(aTo[kk * 65 + sl] + hwOwn[kk]);
        }
        part[(kq << 6) + sl] = ps;
      }
      __syncthreads();
      // reduce 8 waves -> psi_j[s], publish
      if (t < 64) {
        float ps = 0.f;
        #pragma unroll
        for (int w2 = 0; w2 < 8; ++w2) ps += part[(w2 << 6) + t];
        gstoreU64(psiX + ((unsigned)(st & 1) * 16u + b) * 512u + (j << 6) + t,
                  packTV(st + 1, ps));
      }
      // h@Wh^T partial (hides psi-poll latency)
      float pwh = 0.f;
      {
        const float* hp = hL + (q << 6);
        #pragma unroll
        for (int m = 0; m < 16; ++m) {
          float4 h4 = *(const float4*)(hp + 4 * m);
          pwh += whv[m].x * h4.x + whv[m].y * h4.y + whv[m].z * h4.z + whv[m].w * h4.w;
        }
      }
      // poll all 512 psi elements (one per thread)
      {
        const unsigned long long* p = psiX + ((unsigned)(st & 1) * 16u + b) * 512u + t;
        unsigned long long v = gloadU64(p);
        while ((unsigned)(v >> 32) < (unsigned)(st + 1)) v = gloadU64(p);
        psiA[t] = __uint_as_float((unsigned)v);
      }
      __syncthreads();
      // Si assembly + mask + softmax (wave 0)
      if (t < 64) {
        float acc = 0.f;
        #pragma unroll
        for (int w2 = 0; w2 < 8; ++w2) acc += psiA[(w2 << 6) + t];
        float v = mL[t] ? acc : NEGV;
        float mx = v;
        #pragma unroll
        for (int d = 1; d < 64; d <<= 1) mx = fmaxf(mx, __shfl_xor(mx, d));
        float e = __expf(v - mx);
        float ssum = e;
        #pragma unroll
        for (int d = 1; d < 64; d <<= 1) ssum += __shfl_xor(ssum, d);
        attL[t] = e / ssum;
      }
      __syncthreads();
      // g[rl] = Xx + pwh + att@SWM
      {
        float p = pwh;
        const float* sb = swmB + q * 2560 + rl * 20;
        const float* atb = attL + (q << 4);
        #pragma unroll
        for (int i2 = 0; i2 < 4; ++i2) {
          float4 s4 = *(const float4*)(sb + 4 * i2);
          float4 a4 = *(const float4*)(atb + 4 * i2);
          p += s4.x * a4.x + s4.y * a4.y + s4.z * a4.z + s4.w * a4.w;
        }
        p += __shfl_xor(p, 1); p += __shfl_xor(p, 2);
        if (q == 0) gA[rl] = p + xx_r;
      }
      __syncthreads();
      // gates + publish h
      if (t < 32) {
        float gi = gA[t], gf = gA[32 + t], gg = gA[64 + t], go = gA[96 + t];
        c_reg = sigf(gf) * c_reg + sigf(gi) * tanhfast(gg);
        float hn = sigf(go) * tanhfast(c_reg);
        gstoreU64(hx4 + (unsigned)((st + 1) & 1) * 4096u + b * 256 + (j << 5) + t,
                  packTV(st + 1, hn));
      }
    }

    // final classifier (WG j==0 per batch)
    if (j == 0) {
      float v = 0.f;
      if (t < 256) {
        const unsigned long long* p = hx4 + 0 * 4096u + b * 256 + t;  // slot 64&1==0
        unsigned long long vv = gloadU64(p);
        while ((unsigned)(vv >> 32) < 64u) vv = gloadU64(p);
        v = __uint_as_float((unsigned)vv) * fc_w[t];
      }
      #pragma unroll
      for (int d = 1; d < 64; d <<= 1) v += __shfl_xor(v, d);
      if (t < 256 && (t & 63) == 0) redL[t >> 6] = v;
      __syncthreads();
      if (t == 0) out[b] = sigf(redL[0] + redL[1] + redL[2] + redL[3] + fc_b[0]);
    }
  }
}

extern "C" void kernel_launch(void* const* d_in, const int* in_sizes, int n_in,
                              void* d_out, int out_size, void* d_ws, size_t ws_size,
                              hipStream_t stream) {
  const int*   x      = (const int*)d_in[0];
  const int*   mask   = (const int*)d_in[1];
  const float* embed  = (const float*)d_in[3];
  const float* W_ih   = (const float*)d_in[4];
  const float* W_hh   = (const float*)d_in[5];
  const float* b_ih   = (const float*)d_in[6];
  const float* b_hh   = (const float*)d_in[7];
  const float* Ws_w   = (const float*)d_in[8];
  const float* Ws_b   = (const float*)d_in[9];
  const float* Us_w   = (const float*)d_in[10];
  const float* Wx     = (const float*)d_in[12];
  const float* Wh     = (const float*)d_in[13];
  const float* Wm     = (const float*)d_in[14];
  const float* b_cell = (const float*)d_in[15];
  const float* fc_w   = (const float*)d_in[16];
  const float* fc_b   = (const float*)d_in[17];
  float* ws  = (float*)d_ws;
  float* out = (float*)d_out;

  k1_precompute<<<dim3(1152), dim3(256), 0, stream>>>(
      x, embed, W_ih, b_ih, b_hh, Ws_w, Ws_b, Wx, b_cell, ws);
  k_fused<<<dim3(128), dim3(512), 0, stream>>>(
      mask, W_hh, Ws_w, Us_w, Wh, Wm, fc_w, fc_b, ws, out);
}

// Round 12
// 463.083 us; speedup vs baseline: 1.1261x; 1.1261x over previous
//
#include <hip/hip_runtime.h>

#define NEGV -1e9f

// workspace layout (float offsets)
#define OFF_X1   0u               // 1048576  emb@W_ih^T + b (k2-only; k3 reuses head as A_T)
#define OFF_XX   1048576u         // 1048576  emb@Wx^T + b_cell
#define OFF_A    2097152u         // 262144   Aemb = Ws_b + emb@Ws3^T (row-major)
#define OFF_SH   2359296u         // 262144   shared LSTM outputs
#define OFF_SWM  2621440u         // 1048576  shared@Wm^T
#define OFF_HX2  3670016u         // 16384 floats = 8192 u64 (k2 h exchange)
#define OFF_HX4  3686400u         // 16384 floats (k4 h exchange)
#define OFF_PSI  3702784u         // 32768 floats = 2 slots x 16 x 512 u64 (k4 psi exchange)
#define OFF_AT   OFF_X1           // 262144   A transposed [b][k=256][s=64] (written by k3)

__device__ __forceinline__ float sigf(float x) { return 1.f / (1.f + __expf(-x)); }
__device__ __forceinline__ float tanhfast(float x) {
  float e = __expf(2.f * x);
  return 1.f - __fdividef(2.f, e + 1.f);
}

__device__ __forceinline__ unsigned long long gloadU64(const unsigned long long* p) {
  return __hip_atomic_load(p, __ATOMIC_RELAXED, __HIP_MEMORY_SCOPE_AGENT);
}
__device__ __forceinline__ void gstoreU64(unsigned long long* p, unsigned long long v) {
  __hip_atomic_store(p, v, __ATOMIC_RELAXED, __HIP_MEMORY_SCOPE_AGENT);
}
__device__ __forceinline__ unsigned long long packTV(unsigned tag, float v) {
  return ((unsigned long long)tag << 32) | (unsigned long long)__float_as_uint(v);
}

// ---- dual-path exchange: fast = volatile (sc0, served by XCD-shared L2 when
// producer+consumer share an XCD — true for group {b, b+16, ...} under
// round-robin dispatch); slow = agent-scope atomic (LLC, always coherent).
// Publisher writes BOTH (identical value); poller checks fast 7/8 spins and
// the LLC path every 8th -> correct & deadlock-free under ANY WG->XCD mapping.
__device__ __forceinline__ unsigned long long loadFast(const unsigned long long* p) {
  return *(const volatile unsigned long long*)p;
}
__device__ __forceinline__ void storeFast(unsigned long long* p, unsigned long long v) {
  *(volatile unsigned long long*)p = v;
}
__device__ __forceinline__ void pubTV(unsigned long long* p, unsigned long long v) {
  storeFast(p, v);     // fast path first (lowest-latency visibility)
  gstoreU64(p, v);     // LLC path (correctness under any mapping)
}
__device__ __forceinline__ unsigned long long pollTV(const unsigned long long* p,
                                                     unsigned want) {
  unsigned long long v = loadFast(p);
  int k = 0;
  while ((unsigned)(v >> 32) < want) {
    if ((++k & 7) == 0) v = gloadU64(p);   // periodic LLC fallback
    else                v = loadFast(p);
  }
  return v;
}

// 16-row x 128-col output tile GEMM helper, K=256. eL: [16][260], wL: [128][68]
__device__ __forceinline__ void tile_mm(const float* __restrict__ W, int ldw, int wcol0,
                                        int j0, const float* eL, float* wL, float acc[8]) {
  const int i = threadIdx.x >> 4, jj = threadIdx.x & 15;
  for (int kc = 0; kc < 4; ++kc) {
    __syncthreads();
    const int k0 = kc * 64;
    #pragma unroll
    for (int m = 0; m < 32; ++m) {
      int v = threadIdx.x + (m << 8);
      int row = v >> 6, col = v & 63;
      wL[row * 68 + col] = W[(j0 + row) * ldw + wcol0 + k0 + col];
    }
    __syncthreads();
    const float* ebase = eL + i * 260 + k0;
    #pragma unroll 4
    for (int k4 = 0; k4 < 16; ++k4) {
      float4 e4 = *(const float4*)(ebase + k4 * 4);
      #pragma unroll
      for (int u = 0; u < 8; ++u) {
        float4 w4 = *(const float4*)(wL + (jj + (u << 4)) * 68 + k4 * 4);
        acc[u] += e4.x * w4.x + e4.y * w4.y + e4.z * w4.z + e4.w * w4.w;
      }
    }
  }
}

// K1: emb gather + X1 = emb@W_ih^T + (b_ih+b_hh); Xx = emb@Wx^T + b_cell;
//     Aemb = emb@Ws3^T + Ws_b. Zero-inits all exchange buffers.
__global__ __launch_bounds__(256) void k1_precompute(
    const int* __restrict__ x, const float* __restrict__ embed,
    const float* __restrict__ W_ih, const float* __restrict__ b_ih,
    const float* __restrict__ b_hh, const float* __restrict__ Ws_w,
    const float* __restrict__ Ws_b, const float* __restrict__ Wx,
    const float* __restrict__ b_cell, float* __restrict__ ws) {
  __shared__ float eL[16 * 260];
  __shared__ float wL[128 * 68];
  const int rt = blockIdx.x / 18, jb = blockIdx.x % 18;
  if (blockIdx.x == 0) {
    for (int i = threadIdx.x; i < 65536; i += 256) ws[OFF_HX2 + i] = 0.f;
  }
  for (int i = 0; i < 16; ++i) {
    int xi = x[rt * 16 + i];
    eL[i * 260 + threadIdx.x] = embed[xi * 256 + threadIdx.x];
  }
  const float* W; const float* bias1; const float* bias2 = nullptr;
  int ldw, wcol0, j0, ostride; float* out;
  if (jb < 8)       { W = W_ih; ldw = 256; wcol0 = 0;   j0 = jb * 128;        out = ws + OFF_X1; ostride = 1024; bias1 = b_ih; bias2 = b_hh; }
  else if (jb < 16) { W = Wx;   ldw = 256; wcol0 = 0;   j0 = (jb - 8) * 128;  out = ws + OFF_XX; ostride = 1024; bias1 = b_cell; }
  else              { W = Ws_w; ldw = 768; wcol0 = 512; j0 = (jb - 16) * 128; out = ws + OFF_A;  ostride = 256;  bias1 = Ws_b; }
  float acc[8];
  #pragma unroll
  for (int u = 0; u < 8; ++u) acc[u] = 0.f;
  tile_mm(W, ldw, wcol0, j0, eL, wL, acc);
  const int i = threadIdx.x >> 4, jj = threadIdx.x & 15;
  const int r = rt * 16 + i;
  #pragma unroll
  for (int u = 0; u < 8; ++u) {
    int j = j0 + jj + (u << 4);
    float bv = bias1[j] + (bias2 ? bias2[j] : 0.f);
    out[r * ostride + j] = acc[u] + bv;
  }
}

// K2: shared LSTM. grid 128 = 16 batches x 8 WGs, 512 threads.
// W_hh quarter-rows = 64 VGPRs persistent; dual-path h exchange.
__global__ __launch_bounds__(512) void k2_shared_lstm(
    const float* __restrict__ W_hh, float* __restrict__ ws) {
  const int b = blockIdx.x & 15, j = blockIdx.x >> 4;
  const int t = threadIdx.x;
  const int rl = t >> 2, q = t & 3;            // rl 0..127, q 0..3
  const int grow = ((rl >> 5) << 8) + (j << 5) + (rl & 31);
  __shared__ float x1L[64 * 128];
  __shared__ __align__(16) float hL[256];
  __shared__ float gA[128];
  unsigned long long* hx = (unsigned long long*)(ws + OFF_HX2);
  float* sh = ws + OFF_SH;
  const float* X1 = ws + OFF_X1;

  float4 wv[16];
  {
    const float* wp = W_hh + grow * 256 + (q << 6);
    #pragma unroll
    for (int m = 0; m < 16; ++m) wv[m] = *(const float4*)(wp + 4 * m);
  }
  for (int v = t; v < 8192; v += 512) {
    int st = v >> 7, r = v & 127;
    int col = ((r >> 5) << 8) + (j << 5) + (r & 31);
    x1L[v] = X1[(b * 64 + st) * 1024 + col];
  }
  float c_reg = 0.f;
  __syncthreads();

  for (int st = 0; st < 64; ++st) {
    if (t < 256) {
      unsigned long long v =
          pollTV(hx + (unsigned)(st & 1) * 4096u + b * 256 + t, (unsigned)st);
      hL[t] = __uint_as_float((unsigned)v);
    }
    __syncthreads();
    float p = 0.f;
    const float* hp = hL + (q << 6);
    #pragma unroll
    for (int m = 0; m < 16; ++m) {
      float4 h4 = *(const float4*)(hp + 4 * m);
      p += wv[m].x * h4.x + wv[m].y * h4.y + wv[m].z * h4.z + wv[m].w * h4.w;
    }
    p += __shfl_xor(p, 1); p += __shfl_xor(p, 2);
    if (q == 0) gA[rl] = p + x1L[st * 128 + rl];
    __syncthreads();
    if (t < 32) {
      float gi = gA[t], gf = gA[32 + t], gg = gA[64 + t], go = gA[96 + t];
      c_reg = sigf(gf) * c_reg + sigf(gi) * tanhfast(gg);
      float hn = sigf(go) * tanhfast(c_reg);
      sh[(b * 64 + st) * 256 + (j << 5) + t] = hn;
      pubTV(hx + (unsigned)((st + 1) & 1) * 4096u + b * 256 + (j << 5) + t,
            packTV(st + 1, hn));
    }
  }
}

// K3: A_T[b][k][s] = Aemb + shared@Ws1^T (transposed into dead X1 head);
//     SWM = shared@Wm^T (row-major).
__global__ __launch_bounds__(256) void k3_precompute2(
    const float* __restrict__ Ws_w, const float* __restrict__ Wm,
    float* __restrict__ ws) {
  __shared__ float eL[16 * 260];
  __shared__ float wL[128 * 68];
  const int rt = blockIdx.x / 10, jb = blockIdx.x % 10;
  const float* sh = ws + OFF_SH;
  for (int i = 0; i < 16; ++i)
    eL[i * 260 + threadIdx.x] = sh[(rt * 16 + i) * 256 + threadIdx.x];
  const float* W; int ldw, wcol0, j0; bool addmode;
  if (jb < 8) { W = Wm;   ldw = 256; wcol0 = 0; j0 = jb * 128;       addmode = false; }
  else        { W = Ws_w; ldw = 768; wcol0 = 0; j0 = (jb - 8) * 128; addmode = true; }
  float acc[8];
  #pragma unroll
  for (int u = 0; u < 8; ++u) acc[u] = 0.f;
  tile_mm(W, ldw, wcol0, j0, eL, wL, acc);
  const int i = threadIdx.x >> 4, jj = threadIdx.x & 15;
  const int r = rt * 16 + i;
  if (addmode) {
    const float* Aemb = ws + OFF_A;
    float* AT = ws + OFF_AT;
    const int bb = r >> 6, s = r & 63;
    #pragma unroll
    for (int u = 0; u < 8; ++u) {
      int j = j0 + jj + (u << 4);
      AT[bb * 16384 + j * 64 + s] = Aemb[r * 256 + j] + acc[u];
    }
  } else {
    float* out = ws + OFF_SWM;
    #pragma unroll
    for (int u = 0; u < 8; ++u) {
      int j = j0 + jj + (u << 4);
      out[r * 1024 + j] = acc[u];
    }
  }
}

// K4: task LSTM + attention. grid 128 = 16 batches x 8 WGs, 512 threads.
// R5 structure (distributed hw + psi exchange, ~96 VGPR, no spill) with
// dual-path h and psi exchanges.
__global__ __launch_bounds__(512) void k4_task_lstm(
    const int* __restrict__ mask, const float* __restrict__ Ws_w,
    const float* __restrict__ Us_w, const float* __restrict__ Wh,
    const float* __restrict__ fc_w, const float* __restrict__ fc_b,
    float* __restrict__ ws, float* __restrict__ out) {
  const int b = blockIdx.x & 15, j = blockIdx.x >> 4;
  const int t = threadIdx.x;
  const int rl = t >> 2, q = t & 3;                     // g rows: rl 0..127
  const int grow = ((rl >> 5) << 8) + (j << 5) + (rl & 31);
  const int hwrow = t >> 4, hwc = t & 15;               // hw: 32 rows x 16 cols-of-16
  const int kq = t >> 6, sl = t & 63;                   // psi: wave k-subchunk / s lane

  __shared__ __align__(16) float swmB[4 * 128 * 20];    // 40960 B [s/16][rl][16]
  __shared__ __align__(16) float aTo[32 * 65];          // 8320 B  own A^T chunk [kk][s]
  __shared__ __align__(16) float hL[256];
  __shared__ float hwOwn[32];
  __shared__ float usOwn[32];
  __shared__ float part[8 * 64];
  __shared__ float psiA[512];
  __shared__ __align__(16) float attL[64];
  __shared__ float gA[128];
  __shared__ float redL[4];
  __shared__ int   mL[64];

  unsigned long long* hx   = (unsigned long long*)(ws + OFF_HX4);
  unsigned long long* psiX = (unsigned long long*)(ws + OFF_PSI);
  const float* AT  = ws + OFF_AT;
  const float* SWM = ws + OFF_SWM;
  const float* Xx  = ws + OFF_XX;

  // ---- weights into registers (~80 VGPR persistent) ----
  float4 w2v[4];    // Ws2 row (32j+hwrow), cols hwc*16..+16
  {
    const float* p2 = Ws_w + (j * 32 + hwrow) * 768 + 256 + (hwc << 4);
    #pragma unroll
    for (int m = 0; m < 4; ++m) w2v[m] = *(const float4*)(p2 + 4 * m);
  }
  float4 whv[16];   // Wh quarter-row (grow, cols q*64..+64)
  {
    const float* pw = Wh + grow * 256 + (q << 6);
    #pragma unroll
    for (int m = 0; m < 16; ++m) whv[m] = *(const float4*)(pw + 4 * m);
  }
  // ---- LDS staging ----
  for (int v = t; v < 2048; v += 512)   // own A^T k-chunk, coalesced
    aTo[(v >> 6) * 65 + (v & 63)] = AT[b * 16384 + j * 2048 + v];
  for (int v = t; v < 8192; v += 512) {
    int s = v >> 7, r = v & 127;
    int col = ((r >> 5) << 8) + (j << 5) + (r & 31);
    swmB[(s >> 4) * 2560 + r * 20 + (s & 15)] = SWM[(b * 64 + s) * 1024 + col];
  }
  if (t < 32) usOwn[t] = Us_w[j * 32 + t];
  if (t < 64) mL[t] = mask[b * 64 + t];
  float c_reg = 0.f;
  __syncthreads();

  for (int st = 0; st < 64; ++st) {
    // early register prefetch of this step's Xx element (used at end of g)
    float xx_r = 0.f;
    if (q == 0) xx_r = Xx[(b * 64 + st) * 1024 + grow];
    // ---- poll h (own element, dual-path) ----
    if (t < 256) {
      unsigned long long v =
          pollTV(hx + (unsigned)(st & 1) * 4096u + b * 256 + t, (unsigned)st);
      hL[t] = __uint_as_float((unsigned)v);
    }
    __syncthreads();
    // ---- hw own rows: hw[32j+r] = h . Ws2[32j+r], 16 threads/row ----
    {
      const float* hp = hL + (hwc << 4);
      float p = 0.f;
      #pragma unroll
      for (int m = 0; m < 4; ++m) {
        float4 h4 = *(const float4*)(hp + 4 * m);
        p += w2v[m].x * h4.x + w2v[m].y * h4.y + w2v[m].z * h4.z + w2v[m].w * h4.w;
      }
      p += __shfl_xor(p, 1); p += __shfl_xor(p, 2);
      p += __shfl_xor(p, 4); p += __shfl_xor(p, 8);
      if (hwc == 0) hwOwn[hwrow] = p;
    }
    __syncthreads();
    // ---- psi partials over own k-chunk: lane owns s, wave owns 4 k's ----
    {
      float ps = 0.f;
      #pragma unroll
      for (int i2 = 0; i2 < 4; ++i2) {
        int kk = (kq << 2) + i2;
        ps += usOwn[kk] * tanhfast(aTo[kk * 65 + sl] + hwOwn[kk]);
      }
      part[(kq << 6) + sl] = ps;
    }
    __syncthreads();
    // ---- reduce 8 waves -> psi_j[s], publish (dual-path) ----
    if (t < 64) {
      float ps = 0.f;
      #pragma unroll
      for (int w = 0; w < 8; ++w) ps += part[(w << 6) + t];
      pubTV(psiX + ((unsigned)(st & 1) * 16u + b) * 512u + (j << 6) + t,
            packTV(st + 1, ps));
    }
    // ---- h@Wh^T partial (independent of attention; hides psi-poll latency) --
    float pwh = 0.f;
    {
      const float* hp = hL + (q << 6);
      #pragma unroll
      for (int m = 0; m < 16; ++m) {
        float4 h4 = *(const float4*)(hp + 4 * m);
        pwh += whv[m].x * h4.x + whv[m].y * h4.y + whv[m].z * h4.z + whv[m].w * h4.w;
      }
    }
    // ---- poll all 512 psi elements (one per thread, dual-path) ----
    {
      unsigned long long v =
          pollTV(psiX + ((unsigned)(st & 1) * 16u + b) * 512u + t,
                 (unsigned)(st + 1));
      psiA[t] = __uint_as_float((unsigned)v);
    }
    __syncthreads();
    // ---- Si assembly + mask + softmax (wave 0) ----
    if (t < 64) {
      float acc = 0.f;
      #pragma unroll
      for (int w = 0; w < 8; ++w) acc += psiA[(w << 6) + t];
      float v = mL[t] ? acc : NEGV;
      float mx = v;
      #pragma unroll
      for (int d = 1; d < 64; d <<= 1) mx = fmaxf(mx, __shfl_xor(mx, d));
      float e = __expf(v - mx);
      float ssum = e;
      #pragma unroll
      for (int d = 1; d < 64; d <<= 1) ssum += __shfl_xor(ssum, d);
      attL[t] = e / ssum;
    }
    __syncthreads();
    // ---- g[rl] = Xx + pwh + att@SWM (quarter dots, reduce over q) ----
    {
      float p = pwh;
      const float* sb = swmB + q * 2560 + rl * 20;
      const float* atb = attL + (q << 4);
      #pragma unroll
      for (int i2 = 0; i2 < 4; ++i2) {
        float4 s4 = *(const float4*)(sb + 4 * i2);
        float4 a4 = *(const float4*)(atb + 4 * i2);
        p += s4.x * a4.x + s4.y * a4.y + s4.z * a4.z + s4.w * a4.w;
      }
      p += __shfl_xor(p, 1); p += __shfl_xor(p, 2);
      if (q == 0) gA[rl] = p + xx_r;
    }
    __syncthreads();
    // ---- gates + publish h (dual-path) ----
    if (t < 32) {
      float gi = gA[t], gf = gA[32 + t], gg = gA[64 + t], go = gA[96 + t];
      c_reg = sigf(gf) * c_reg + sigf(gi) * tanhfast(gg);
      float hn = sigf(go) * tanhfast(c_reg);
      pubTV(hx + (unsigned)((st + 1) & 1) * 4096u + b * 256 + (j << 5) + t,
            packTV(st + 1, hn));
    }
  }

  // ---- final classifier (WG j==0 per batch) ----
  if (j == 0) {
    float v = 0.f;
    if (t < 256) {
      unsigned long long vv = pollTV(hx + 0 * 4096u + b * 256 + t, 64u);
      v = __uint_as_float((unsigned)vv) * fc_w[t];
    }
    #pragma unroll
    for (int d = 1; d < 64; d <<= 1) v += __shfl_xor(v, d);
    if (t < 256 && (t & 63) == 0) redL[t >> 6] = v;
    __syncthreads();
    if (t == 0) out[b] = sigf(redL[0] + redL[1] + redL[2] + redL[3] + fc_b[0]);
  }
}

extern "C" void kernel_launch(void* const* d_in, const int* in_sizes, int n_in,
                              void* d_out, int out_size, void* d_ws, size_t ws_size,
                              hipStream_t stream) {
  const int*   x      = (const int*)d_in[0];
  const int*   mask   = (const int*)d_in[1];
  const float* embed  = (const float*)d_in[3];
  const float* W_ih   = (const float*)d_in[4];
  const float* W_hh   = (const float*)d_in[5];
  const float* b_ih   = (const float*)d_in[6];
  const float* b_hh   = (const float*)d_in[7];
  const float* Ws_w   = (const float*)d_in[8];
  const float* Ws_b   = (const float*)d_in[9];
  const float* Us_w   = (const float*)d_in[10];
  const float* Wx     = (const float*)d_in[12];
  const float* Wh     = (const float*)d_in[13];
  const float* Wm     = (const float*)d_in[14];
  const float* b_cell = (const float*)d_in[15];
  const float* fc_w   = (const float*)d_in[16];
  const float* fc_b   = (const float*)d_in[17];
  float* ws  = (float*)d_ws;
  float* out = (float*)d_out;

  k1_precompute<<<dim3(1152), dim3(256), 0, stream>>>(
      x, embed, W_ih, b_ih, b_hh, Ws_w, Ws_b, Wx, b_cell, ws);
  k2_shared_lstm<<<dim3(128), dim3(512), 0, stream>>>(W_hh, ws);
  k3_precompute2<<<dim3(640), dim3(256), 0, stream>>>(Ws_w, Wm, ws);
  k4_task_lstm<<<dim3(128), dim3(512), 0, stream>>>(
      mask, Ws_w, Us_w, Wh, fc_w, fc_b, ws, out);
}

// Round 13
// 447.580 us; speedup vs baseline: 1.1651x; 1.0346x over previous
//
#include <hip/hip_runtime.h>

#define NEGV -1e9f

// workspace layout (float offsets)
#define OFF_X1   0u               // 1048576  emb@W_ih^T + b (k2-only; k3 reuses head as A_T)
#define OFF_XX   1048576u         // 1048576  emb@Wx^T + b_cell
#define OFF_A    2097152u         // 262144   Aemb = Ws_b + emb@Ws3^T (row-major)
#define OFF_SH   2359296u         // 262144   shared LSTM outputs
#define OFF_SWM  2621440u         // 1048576  shared@Wm^T
#define OFF_HX2  3670016u         // 16384 floats = 8192 u64 (k2 h exchange)
#define OFF_HX4  3686400u         // 16384 floats (k4 h exchange)
#define OFF_PSI  3702784u         // 32768 floats = 2 slots x 16 x 512 u64 (k4 psi exchange)
#define OFF_AT   OFF_X1           // 262144   A transposed [b][k=256][s=64] (written by k3)

__device__ __forceinline__ float sigf(float x) { return 1.f / (1.f + __expf(-x)); }
__device__ __forceinline__ float tanhfast(float x) {
  float e = __expf(2.f * x);
  return 1.f - __fdividef(2.f, e + 1.f);
}

__device__ __forceinline__ unsigned long long gloadU64(const unsigned long long* p) {
  return __hip_atomic_load(p, __ATOMIC_RELAXED, __HIP_MEMORY_SCOPE_AGENT);
}
__device__ __forceinline__ void gstoreU64(unsigned long long* p, unsigned long long v) {
  __hip_atomic_store(p, v, __ATOMIC_RELAXED, __HIP_MEMORY_SCOPE_AGENT);
}
__device__ __forceinline__ unsigned long long packTV(unsigned tag, float v) {
  return ((unsigned long long)tag << 32) | (unsigned long long)__float_as_uint(v);
}

// Pipelined poll: 4 outstanding loads to the same address overlap their
// round trips; check-in-issue-order waits only vmcnt(3-i) -> detect
// granularity ~1/4 of a serial spin. Tags are monotonic so any hit is safe.
__device__ __forceinline__ unsigned long long pollTV(const unsigned long long* p,
                                                     unsigned want) {
  unsigned long long v = gloadU64(p);
  if ((unsigned)(v >> 32) >= want) return v;
  for (;;) {
    unsigned long long a = gloadU64(p);
    unsigned long long b = gloadU64(p);
    unsigned long long c = gloadU64(p);
    unsigned long long d = gloadU64(p);
    if ((unsigned)(a >> 32) >= want) return a;
    if ((unsigned)(b >> 32) >= want) return b;
    if ((unsigned)(c >> 32) >= want) return c;
    if ((unsigned)(d >> 32) >= want) return d;
  }
}

// 16-row x 128-col output tile GEMM helper, K=256. eL: [16][260], wL: [128][68]
__device__ __forceinline__ void tile_mm(const float* __restrict__ W, int ldw, int wcol0,
                                        int j0, const float* eL, float* wL, float acc[8]) {
  const int i = threadIdx.x >> 4, jj = threadIdx.x & 15;
  for (int kc = 0; kc < 4; ++kc) {
    __syncthreads();
    const int k0 = kc * 64;
    #pragma unroll
    for (int m = 0; m < 32; ++m) {
      int v = threadIdx.x + (m << 8);
      int row = v >> 6, col = v & 63;
      wL[row * 68 + col] = W[(j0 + row) * ldw + wcol0 + k0 + col];
    }
    __syncthreads();
    const float* ebase = eL + i * 260 + k0;
    #pragma unroll 4
    for (int k4 = 0; k4 < 16; ++k4) {
      float4 e4 = *(const float4*)(ebase + k4 * 4);
      #pragma unroll
      for (int u = 0; u < 8; ++u) {
        float4 w4 = *(const float4*)(wL + (jj + (u << 4)) * 68 + k4 * 4);
        acc[u] += e4.x * w4.x + e4.y * w4.y + e4.z * w4.z + e4.w * w4.w;
      }
    }
  }
}

// K1: emb gather + X1 = emb@W_ih^T + (b_ih+b_hh); Xx = emb@Wx^T + b_cell;
//     Aemb = emb@Ws3^T + Ws_b. Zero-inits all exchange buffers.
__global__ __launch_bounds__(256) void k1_precompute(
    const int* __restrict__ x, const float* __restrict__ embed,
    const float* __restrict__ W_ih, const float* __restrict__ b_ih,
    const float* __restrict__ b_hh, const float* __restrict__ Ws_w,
    const float* __restrict__ Ws_b, const float* __restrict__ Wx,
    const float* __restrict__ b_cell, float* __restrict__ ws) {
  __shared__ float eL[16 * 260];
  __shared__ float wL[128 * 68];
  const int rt = blockIdx.x / 18, jb = blockIdx.x % 18;
  if (blockIdx.x == 0) {
    for (int i = threadIdx.x; i < 65536; i += 256) ws[OFF_HX2 + i] = 0.f;
  }
  for (int i = 0; i < 16; ++i) {
    int xi = x[rt * 16 + i];
    eL[i * 260 + threadIdx.x] = embed[xi * 256 + threadIdx.x];
  }
  const float* W; const float* bias1; const float* bias2 = nullptr;
  int ldw, wcol0, j0, ostride; float* out;
  if (jb < 8)       { W = W_ih; ldw = 256; wcol0 = 0;   j0 = jb * 128;        out = ws + OFF_X1; ostride = 1024; bias1 = b_ih; bias2 = b_hh; }
  else if (jb < 16) { W = Wx;   ldw = 256; wcol0 = 0;   j0 = (jb - 8) * 128;  out = ws + OFF_XX; ostride = 1024; bias1 = b_cell; }
  else              { W = Ws_w; ldw = 768; wcol0 = 512; j0 = (jb - 16) * 128; out = ws + OFF_A;  ostride = 256;  bias1 = Ws_b; }
  float acc[8];
  #pragma unroll
  for (int u = 0; u < 8; ++u) acc[u] = 0.f;
  tile_mm(W, ldw, wcol0, j0, eL, wL, acc);
  const int i = threadIdx.x >> 4, jj = threadIdx.x & 15;
  const int r = rt * 16 + i;
  #pragma unroll
  for (int u = 0; u < 8; ++u) {
    int j = j0 + jj + (u << 4);
    float bv = bias1[j] + (bias2 ? bias2[j] : 0.f);
    out[r * ostride + j] = acc[u] + bv;
  }
}

// K2: shared LSTM. grid 128 = 16 batches x 8 WGs, 512 threads.
// W_hh quarter-rows = 64 VGPRs persistent; pipelined-poll h exchange.
__global__ __launch_bounds__(512) void k2_shared_lstm(
    const float* __restrict__ W_hh, float* __restrict__ ws) {
  const int b = blockIdx.x & 15, j = blockIdx.x >> 4;
  const int t = threadIdx.x;
  const int rl = t >> 2, q = t & 3;            // rl 0..127, q 0..3
  const int grow = ((rl >> 5) << 8) + (j << 5) + (rl & 31);
  __shared__ float x1L[64 * 128];
  __shared__ __align__(16) float hL[256];
  __shared__ float gA[128];
  unsigned long long* hx = (unsigned long long*)(ws + OFF_HX2);
  float* sh = ws + OFF_SH;
  const float* X1 = ws + OFF_X1;

  float4 wv[16];
  {
    const float* wp = W_hh + grow * 256 + (q << 6);
    #pragma unroll
    for (int m = 0; m < 16; ++m) wv[m] = *(const float4*)(wp + 4 * m);
  }
  for (int v = t; v < 8192; v += 512) {
    int st = v >> 7, r = v & 127;
    int col = ((r >> 5) << 8) + (j << 5) + (r & 31);
    x1L[v] = X1[(b * 64 + st) * 1024 + col];
  }
  float c_reg = 0.f;
  __syncthreads();

  for (int st = 0; st < 64; ++st) {
    if (t < 256) {
      unsigned long long v =
          pollTV(hx + (unsigned)(st & 1) * 4096u + b * 256 + t, (unsigned)st);
      hL[t] = __uint_as_float((unsigned)v);
    }
    __syncthreads();
    float p = 0.f;
    const float* hp = hL + (q << 6);
    #pragma unroll
    for (int m = 0; m < 16; ++m) {
      float4 h4 = *(const float4*)(hp + 4 * m);
      p += wv[m].x * h4.x + wv[m].y * h4.y + wv[m].z * h4.z + wv[m].w * h4.w;
    }
    p += __shfl_xor(p, 1); p += __shfl_xor(p, 2);
    if (q == 0) gA[rl] = p + x1L[st * 128 + rl];
    __syncthreads();
    if (t < 32) {
      float gi = gA[t], gf = gA[32 + t], gg = gA[64 + t], go = gA[96 + t];
      c_reg = sigf(gf) * c_reg + sigf(gi) * tanhfast(gg);
      float hn = sigf(go) * tanhfast(c_reg);
      sh[(b * 64 + st) * 256 + (j << 5) + t] = hn;
      gstoreU64(hx + (unsigned)((st + 1) & 1) * 4096u + b * 256 + (j << 5) + t,
                packTV(st + 1, hn));
    }
  }
}

// K3: A_T[b][k][s] = Aemb + shared@Ws1^T (transposed into dead X1 head);
//     SWM = shared@Wm^T (row-major).
__global__ __launch_bounds__(256) void k3_precompute2(
    const float* __restrict__ Ws_w, const float* __restrict__ Wm,
    float* __restrict__ ws) {
  __shared__ float eL[16 * 260];
  __shared__ float wL[128 * 68];
  const int rt = blockIdx.x / 10, jb = blockIdx.x % 10;
  const float* sh = ws + OFF_SH;
  for (int i = 0; i < 16; ++i)
    eL[i * 260 + threadIdx.x] = sh[(rt * 16 + i) * 256 + threadIdx.x];
  const float* W; int ldw, wcol0, j0; bool addmode;
  if (jb < 8) { W = Wm;   ldw = 256; wcol0 = 0; j0 = jb * 128;       addmode = false; }
  else        { W = Ws_w; ldw = 768; wcol0 = 0; j0 = (jb - 8) * 128; addmode = true; }
  float acc[8];
  #pragma unroll
  for (int u = 0; u < 8; ++u) acc[u] = 0.f;
  tile_mm(W, ldw, wcol0, j0, eL, wL, acc);
  const int i = threadIdx.x >> 4, jj = threadIdx.x & 15;
  const int r = rt * 16 + i;
  if (addmode) {
    const float* Aemb = ws + OFF_A;
    float* AT = ws + OFF_AT;
    const int bb = r >> 6, s = r & 63;
    #pragma unroll
    for (int u = 0; u < 8; ++u) {
      int j = j0 + jj + (u << 4);
      AT[bb * 16384 + j * 64 + s] = Aemb[r * 256 + j] + acc[u];
    }
  } else {
    float* out = ws + OFF_SWM;
    #pragma unroll
    for (int u = 0; u < 8; ++u) {
      int j = j0 + jj + (u << 4);
      out[r * 1024 + j] = acc[u];
    }
  }
}

// K4: task LSTM + attention. grid 128 = 16 batches x 8 WGs, 512 threads.
// R5 structure (distributed hw + psi exchange, ~96 VGPR, no spill) with
// pipelined-poll h and psi exchanges.
__global__ __launch_bounds__(512) void k4_task_lstm(
    const int* __restrict__ mask, const float* __restrict__ Ws_w,
    const float* __restrict__ Us_w, const float* __restrict__ Wh,
    const float* __restrict__ fc_w, const float* __restrict__ fc_b,
    float* __restrict__ ws, float* __restrict__ out) {
  const int b = blockIdx.x & 15, j = blockIdx.x >> 4;
  const int t = threadIdx.x;
  const int rl = t >> 2, q = t & 3;                     // g rows: rl 0..127
  const int grow = ((rl >> 5) << 8) + (j << 5) + (rl & 31);
  const int hwrow = t >> 4, hwc = t & 15;               // hw: 32 rows x 16 cols-of-16
  const int kq = t >> 6, sl = t & 63;                   // psi: wave k-subchunk / s lane

  __shared__ __align__(16) float swmB[4 * 128 * 20];    // 40960 B [s/16][rl][16]
  __shared__ __align__(16) float aTo[32 * 65];          // 8320 B  own A^T chunk [kk][s]
  __shared__ __align__(16) float hL[256];
  __shared__ float hwOwn[32];
  __shared__ float usOwn[32];
  __shared__ float part[8 * 64];
  __shared__ float psiA[512];
  __shared__ __align__(16) float attL[64];
  __shared__ float gA[128];
  __shared__ float redL[4];
  __shared__ int   mL[64];

  unsigned long long* hx   = (unsigned long long*)(ws + OFF_HX4);
  unsigned long long* psiX = (unsigned long long*)(ws + OFF_PSI);
  const float* AT  = ws + OFF_AT;
  const float* SWM = ws + OFF_SWM;
  const float* Xx  = ws + OFF_XX;

  // ---- weights into registers (~80 VGPR persistent) ----
  float4 w2v[4];    // Ws2 row (32j+hwrow), cols hwc*16..+16
  {
    const float* p2 = Ws_w + (j * 32 + hwrow) * 768 + 256 + (hwc << 4);
    #pragma unroll
    for (int m = 0; m < 4; ++m) w2v[m] = *(const float4*)(p2 + 4 * m);
  }
  float4 whv[16];   // Wh quarter-row (grow, cols q*64..+64)
  {
    const float* pw = Wh + grow * 256 + (q << 6);
    #pragma unroll
    for (int m = 0; m < 16; ++m) whv[m] = *(const float4*)(pw + 4 * m);
  }
  // ---- LDS staging ----
  for (int v = t; v < 2048; v += 512)   // own A^T k-chunk, coalesced
    aTo[(v >> 6) * 65 + (v & 63)] = AT[b * 16384 + j * 2048 + v];
  for (int v = t; v < 8192; v += 512) {
    int s = v >> 7, r = v & 127;
    int col = ((r >> 5) << 8) + (j << 5) + (r & 31);
    swmB[(s >> 4) * 2560 + r * 20 + (s & 15)] = SWM[(b * 64 + s) * 1024 + col];
  }
  if (t < 32) usOwn[t] = Us_w[j * 32 + t];
  if (t < 64) mL[t] = mask[b * 64 + t];
  float c_reg = 0.f;
  __syncthreads();

  for (int st = 0; st < 64; ++st) {
    // early register prefetch of this step's Xx element (used at end of g)
    float xx_r = 0.f;
    if (q == 0) xx_r = Xx[(b * 64 + st) * 1024 + grow];
    // ---- poll h (own element, pipelined) ----
    if (t < 256) {
      unsigned long long v =
          pollTV(hx + (unsigned)(st & 1) * 4096u + b * 256 + t, (unsigned)st);
      hL[t] = __uint_as_float((unsigned)v);
    }
    __syncthreads();
    // ---- hw own rows: hw[32j+r] = h . Ws2[32j+r], 16 threads/row ----
    {
      const float* hp = hL + (hwc << 4);
      float p = 0.f;
      #pragma unroll
      for (int m = 0; m < 4; ++m) {
        float4 h4 = *(const float4*)(hp + 4 * m);
        p += w2v[m].x * h4.x + w2v[m].y * h4.y + w2v[m].z * h4.z + w2v[m].w * h4.w;
      }
      p += __shfl_xor(p, 1); p += __shfl_xor(p, 2);
      p += __shfl_xor(p, 4); p += __shfl_xor(p, 8);
      if (hwc == 0) hwOwn[hwrow] = p;
    }
    __syncthreads();
    // ---- psi partials over own k-chunk: lane owns s, wave owns 4 k's ----
    {
      float ps = 0.f;
      #pragma unroll
      for (int i2 = 0; i2 < 4; ++i2) {
        int kk = (kq << 2) + i2;
        ps += usOwn[kk] * tanhfast(aTo[kk * 65 + sl] + hwOwn[kk]);
      }
      part[(kq << 6) + sl] = ps;
    }
    __syncthreads();
    // ---- reduce 8 waves -> psi_j[s], publish ----
    if (t < 64) {
      float ps = 0.f;
      #pragma unroll
      for (int w = 0; w < 8; ++w) ps += part[(w << 6) + t];
      gstoreU64(psiX + ((unsigned)(st & 1) * 16u + b) * 512u + (j << 6) + t,
                packTV(st + 1, ps));
    }
    // ---- h@Wh^T partial (independent of attention; hides psi-poll latency) --
    float pwh = 0.f;
    {
      const float* hp = hL + (q << 6);
      #pragma unroll
      for (int m = 0; m < 16; ++m) {
        float4 h4 = *(const float4*)(hp + 4 * m);
        pwh += whv[m].x * h4.x + whv[m].y * h4.y + whv[m].z * h4.z + whv[m].w * h4.w;
      }
    }
    // ---- poll all 512 psi elements (one per thread, pipelined) ----
    {
      unsigned long long v =
          pollTV(psiX + ((unsigned)(st & 1) * 16u + b) * 512u + t,
                 (unsigned)(st + 1));
      psiA[t] = __uint_as_float((unsigned)v);
    }
    __syncthreads();
    // ---- Si assembly + mask + softmax (wave 0) ----
    if (t < 64) {
      float acc = 0.f;
      #pragma unroll
      for (int w = 0; w < 8; ++w) acc += psiA[(w << 6) + t];
      float v = mL[t] ? acc : NEGV;
      float mx = v;
      #pragma unroll
      for (int d = 1; d < 64; d <<= 1) mx = fmaxf(mx, __shfl_xor(mx, d));
      float e = __expf(v - mx);
      float ssum = e;
      #pragma unroll
      for (int d = 1; d < 64; d <<= 1) ssum += __shfl_xor(ssum, d);
      attL[t] = e / ssum;
    }
    __syncthreads();
    // ---- g[rl] = Xx + pwh + att@SWM (quarter dots, reduce over q) ----
    {
      float p = pwh;
      const float* sb = swmB + q * 2560 + rl * 20;
      const float* atb = attL + (q << 4);
      #pragma unroll
      for (int i2 = 0; i2 < 4; ++i2) {
        float4 s4 = *(const float4*)(sb + 4 * i2);
        float4 a4 = *(const float4*)(atb + 4 * i2);
        p += s4.x * a4.x + s4.y * a4.y + s4.z * a4.z + s4.w * a4.w;
      }
      p += __shfl_xor(p, 1); p += __shfl_xor(p, 2);
      if (q == 0) gA[rl] = p + xx_r;
    }
    __syncthreads();
    // ---- gates + publish h ----
    if (t < 32) {
      float gi = gA[t], gf = gA[32 + t], gg = gA[64 + t], go = gA[96 + t];
      c_reg = sigf(gf) * c_reg + sigf(gi) * tanhfast(gg);
      float hn = sigf(go) * tanhfast(c_reg);
      gstoreU64(hx + (unsigned)((st + 1) & 1) * 4096u + b * 256 + (j << 5) + t,
                packTV(st + 1, hn));
    }
  }

  // ---- final classifier (WG j==0 per batch) ----
  if (j == 0) {
    float v = 0.f;
    if (t < 256) {
      unsigned long long vv = pollTV(hx + 0 * 4096u + b * 256 + t, 64u);
      v = __uint_as_float((unsigned)vv) * fc_w[t];
    }
    #pragma unroll
    for (int d = 1; d < 64; d <<= 1) v += __shfl_xor(v, d);
    if (t < 256 && (t & 63) == 0) redL[t >> 6] = v;
    __syncthreads();
    if (t == 0) out[b] = sigf(redL[0] + redL[1] + redL[2] + redL[3] + fc_b[0]);
  }
}

extern "C" void kernel_launch(void* const* d_in, const int* in_sizes, int n_in,
                              void* d_out, int out_size, void* d_ws, size_t ws_size,
                              hipStream_t stream) {
  const int*   x      = (const int*)d_in[0];
  const int*   mask   = (const int*)d_in[1];
  const float* embed  = (const float*)d_in[3];
  const float* W_ih   = (const float*)d_in[4];
  const float* W_hh   = (const float*)d_in[5];
  const float* b_ih   = (const float*)d_in[6];
  const float* b_hh   = (const float*)d_in[7];
  const float* Ws_w   = (const float*)d_in[8];
  const float* Ws_b   = (const float*)d_in[9];
  const float* Us_w   = (const float*)d_in[10];
  const float* Wx     = (const float*)d_in[12];
  const float* Wh     = (const float*)d_in[13];
  const float* Wm     = (const float*)d_in[14];
  const float* b_cell = (const float*)d_in[15];
  const float* fc_w   = (const float*)d_in[16];
  const float* fc_b   = (const float*)d_in[17];
  float* ws  = (float*)d_ws;
  float* out = (float*)d_out;

  k1_precompute<<<dim3(1152), dim3(256), 0, stream>>>(
      x, embed, W_ih, b_ih, b_hh, Ws_w, Ws_b, Wx, b_cell, ws);
  k2_shared_lstm<<<dim3(128), dim3(512), 0, stream>>>(W_hh, ws);
  k3_precompute2<<<dim3(640), dim3(256), 0, stream>>>(Ws_w, Wm, ws);
  k4_task_lstm<<<dim3(128), dim3(512), 0, stream>>>(
      mask, Ws_w, Us_w, Wh, fc_w, fc_b, ws, out);
}